// Round 15
// baseline (172.083 us; speedup 1.0000x reference)
//
#include <hip/hip_runtime.h>

#define OUT_SZ 299
#define PLANE (OUT_SZ * OUT_SZ)   // 89401
#define RPB 13                    // output rows per block: 13 * 23 = 299
#define CHUNKS 23
#define TSTRIDE 201               // tmp row stride in dwords (odd; >= wcI+1, wcI<=199)
#define BLK_PER_IMG (16 * 3 * CHUNKS)   // 1104 blocks per image
#define NXCD 8

__global__ __launch_bounds__(320) void crop_resize_kernel(
    const float* __restrict__ x,   // (32, 3, 299, 299)
    const int*   __restrict__ f,   // (32, 16, 4) = tlx, tly, brx, bry
    float*       __restrict__ out) // (32, 16, 3, 299, 299)
{
    __shared__ float tmp[RPB * TSTRIDE];   // 10452 B: row-interped crop rows

    // --- XCD-aware swizzle: all 1104 blocks of an image land on one XCD ---
    // HW: block L -> XCD L%8 (round-robin). XCD k processes images {k, k+8, k+16, k+24}.
    const int L       = blockIdx.x;          // 0..35327
    const int xcd     = L & (NXCD - 1);
    const int W       = L >> 3;              // 0..4415
    const int img_grp = W / BLK_PER_IMG;     // 0..3
    const int within  = W - img_grp * BLK_PER_IMG;   // 0..1103
    const int s       = xcd + (img_grp << 3);        // image 0..31
    const int sgl     = within / (3 * CHUNKS);       // crop 0..15
    const int rem     = within - sgl * (3 * CHUNKS);
    const int c       = rem / CHUNKS;                // channel 0..2
    const int chunk   = rem - c * CHUNKS;            // 0..22
    const int sg      = (s << 4) + sgl;

    const int t = threadIdx.x;

    // Box is block-uniform -> scalar loads.
    const int4 box = *reinterpret_cast<const int4*>(f + (size_t)sg * 4);
    const int tlx = box.x, tly = box.y, brx = box.z, bry = box.w;
    const int hcI = brx - tlx, wcI = bry - tly;
    const float hc = (float)hcI, wc = (float)wcI;

    const int i0 = chunk * RPB;

    // Lane table: lanes 0..12 of EVERY wave hold row info for output row i0+rr.
    // Uniform control flow (all threads execute).
    const int lane = t & 63;
    int v_r0e, v_r1e;
    float v_wr;
    {
        float sr  = fminf(fmaxf(((float)(i0 + lane) + 0.5f) * hc / (float)OUT_SZ
                                - 0.5f, 0.0f), hc - 1.0f);
        float r0f = floorf(sr);
        v_wr = sr - r0f;
        int r0l = (int)r0f;
        int r1l = min(r0l + 1, hcI - 1);
        v_r0e = (r0l + tlx) * OUT_SZ + tly;   // plane-local offset of crop row r0
        v_r1e = (r1l + tlx) * OUT_SZ + tly;
    }

    // Hoist ALL readlanes into uniform control flow (convergent-op safety).
    // 39 wave-uniform scalars, statically indexed -> SGPRs.
    int   sr0e[RPB], sr1e[RPB];
    float srw[RPB];
    #pragma unroll
    for (int rr = 0; rr < RPB; ++rr) {
        sr0e[rr] = __builtin_amdgcn_readlane(v_r0e, rr);
        sr1e[rr] = __builtin_amdgcn_readlane(v_r1e, rr);
        srw[rr]  = __int_as_float(
                       __builtin_amdgcn_readlane(__float_as_int(v_wr), rr));
    }

    // Per-output-column precompute (registers only).
    float sc  = fminf(fmaxf(((float)t + 0.5f) * wc / (float)OUT_SZ - 0.5f,
                            0.0f), wc - 1.0f);
    float c0f = floorf(sc);
    const int   c0  = (int)c0f;          // crop-local, in [0, wcI-1]
    const float wcl = sc - c0f;
    const int   jl  = min(t, wcI - 1);   // phase-1 load col (t==wcI -> pad dup)

    const float* __restrict__ img = x + ((size_t)s * 3 + (size_t)c) * PLANE;

    // Phase 1: vertical (row) interp over crop columns — COALESCED loads.
    if (t <= wcI) {                      // plain loads/stores only inside
        #pragma unroll
        for (int rr = 0; rr < RPB; ++rr) {
            float a = img[sr0e[rr] + jl];    // scalar base + lane index
            float b = img[sr1e[rr] + jl];
            tmp[rr * TSTRIDE + t] = a + srw[rr] * (b - a);
        }
    }
    __syncthreads();
    if (t >= OUT_SZ) return;

    // Phase 2: horizontal (col) interp — ds_read2_b32 + 2 FMA + nt-store per px.
    // Output is write-once-never-read: nontemporal keeps it out of L2 so the
    // swizzle-won image residency survives.
    float* __restrict__ orow = out + ((size_t)sg * 3 + (size_t)c) * PLANE
                             + (size_t)i0 * OUT_SZ + t;
    #pragma unroll
    for (int rr = 0; rr < RPB; ++rr) {
        const float* p = tmp + rr * TSTRIDE + c0;
        float hA = p[0];
        float hB = p[1];   // adjacent dword; pad col makes c1-clamp exact
        __builtin_nontemporal_store(hA + wcl * (hB - hA),
                                    orow + (size_t)rr * OUT_SZ);
    }
}

extern "C" void kernel_launch(void* const* d_in, const int* in_sizes, int n_in,
                              void* d_out, int out_size, void* d_ws, size_t ws_size,
                              hipStream_t stream) {
    const float* x   = (const float*)d_in[0];  // (32,3,299,299) fp32
    const int*   f   = (const int*)  d_in[1];  // (32,16,4) int32
    float*       out = (float*)d_out;          // (32,16,3,299,299) fp32

    const int nblocks = NXCD * 4 * BLK_PER_IMG;   // 35328 = 23*3*512
    crop_resize_kernel<<<nblocks, 320, 0, stream>>>(x, f, out);
}

// Round 16
// 166.034 us; speedup vs baseline: 1.0364x; 1.0364x over previous
//
#include <hip/hip_runtime.h>

#define OUT_SZ 299
#define PLANE (OUT_SZ * OUT_SZ)   // 89401
#define RPB 13                    // output rows per block: 13 * 23 = 299
#define CHUNKS 23
#define TSTRIDE 201               // tmp row stride in dwords (odd; >= wcI+1, wcI<=199)
#define SPAN (RPB * OUT_SZ)       // 3887 dwords: block's contiguous output span
#define BLK_PER_IMG (16 * 3 * CHUNKS)   // 1104 blocks per image
#define NXCD 8
#define NTHR 320

__global__ __launch_bounds__(NTHR) void crop_resize_kernel(
    const float* __restrict__ x,   // (32, 3, 299, 299)
    const int*   __restrict__ f,   // (32, 16, 4) = tlx, tly, brx, bry
    float*       __restrict__ out) // (32, 16, 3, 299, 299)
{
    __shared__ float tmp[RPB * TSTRIDE];   // 10452 B: row-interped crop rows

    // --- XCD-aware swizzle: all 1104 blocks of an image land on one XCD ---
    const int L       = blockIdx.x;          // 0..35327
    const int xcd     = L & (NXCD - 1);
    const int W       = L >> 3;              // 0..4415
    const int img_grp = W / BLK_PER_IMG;     // 0..3
    const int within  = W - img_grp * BLK_PER_IMG;   // 0..1103
    const int s       = xcd + (img_grp << 3);        // image 0..31
    const int sgl     = within / (3 * CHUNKS);       // crop 0..15
    const int rem     = within - sgl * (3 * CHUNKS);
    const int c       = rem / CHUNKS;                // channel 0..2
    const int chunk   = rem - c * CHUNKS;            // 0..22
    const int sg      = (s << 4) + sgl;

    const int t = threadIdx.x;

    // Box is block-uniform -> scalar loads.
    const int4 box = *reinterpret_cast<const int4*>(f + (size_t)sg * 4);
    const int tlx = box.x, tly = box.y, brx = box.z, bry = box.w;
    const int hcI = brx - tlx, wcI = bry - tly;
    const float hc = (float)hcI, wc = (float)wcI;

    const int i0 = chunk * RPB;

    // Lane table: lanes 0..12 of EVERY wave hold row info for output row i0+rr.
    const int lane = t & 63;
    int v_r0e, v_r1e;
    float v_wr;
    {
        float sr  = fminf(fmaxf(((float)(i0 + lane) + 0.5f) * hc / (float)OUT_SZ
                                - 0.5f, 0.0f), hc - 1.0f);
        float r0f = floorf(sr);
        v_wr = sr - r0f;
        int r0l = (int)r0f;
        int r1l = min(r0l + 1, hcI - 1);
        v_r0e = (r0l + tlx) * OUT_SZ + tly;
        v_r1e = (r1l + tlx) * OUT_SZ + tly;
    }

    // Hoist ALL readlanes into uniform control flow (convergent-op safety).
    int   sr0e[RPB], sr1e[RPB];
    float srw[RPB];
    #pragma unroll
    for (int rr = 0; rr < RPB; ++rr) {
        sr0e[rr] = __builtin_amdgcn_readlane(v_r0e, rr);
        sr1e[rr] = __builtin_amdgcn_readlane(v_r1e, rr);
        srw[rr]  = __int_as_float(
                       __builtin_amdgcn_readlane(__float_as_int(v_wr), rr));
    }

    const float* __restrict__ img = x + ((size_t)s * 3 + (size_t)c) * PLANE;
    const int jl = min(t, wcI - 1);      // phase-1 load col (t==wcI -> pad dup)

    // Phase 1: vertical (row) interp over crop columns — COALESCED loads.
    if (t <= wcI) {
        #pragma unroll
        for (int rr = 0; rr < RPB; ++rr) {
            float a = img[sr0e[rr] + jl];
            float b = img[sr1e[rr] + jl];
            tmp[rr * TSTRIDE + t] = a + srw[rr] * (b - a);
        }
    }
    __syncthreads();

    // Phase 2: horizontal interp over the block's CONTIGUOUS 3887-dword span,
    // written with ALIGNED dwordx4 stores (head/tail scalar).
    const size_t spanBase = ((size_t)sg * 3 + (size_t)c) * PLANE
                          + (size_t)i0 * OUT_SZ;
    float* __restrict__ ospan = out + spanBase;

    const float wscale = wc / (float)OUT_SZ;
    const float wmax   = wc - 1.0f;

    // per-element evaluator (flat span offset w -> pixel value)
    auto pix = [&](int w) -> float {
        int rr = (int)((unsigned)w / OUT_SZ);
        int j  = w - rr * OUT_SZ;
        float scf = fminf(fmaxf(((float)j + 0.5f) * wscale - 0.5f, 0.0f), wmax);
        float cf  = floorf(scf);
        int   cc  = (int)cf;
        float wl  = scf - cf;
        const float* p = tmp + rr * TSTRIDE + cc;
        return p[0] + wl * (p[1] - p[0]);
    };

    const int a0    = (int)((4 - (spanBase & 3)) & 3);   // head elems to align
    const int nq    = (SPAN - a0) >> 2;                  // aligned quads (971)
    const int tail0 = a0 + (nq << 2);

    if (t < a0)           ospan[t] = pix(t);                     // head (<=3)
    if (t < SPAN - tail0) ospan[tail0 + t] = pix(tail0 + t);     // tail (<=3)

    for (int q = t; q < nq; q += NTHR) {
        const int w  = a0 + (q << 2);
        const int rr = (int)((unsigned)w / OUT_SZ);
        const int j  = w - rr * OUT_SZ;
        float v0, v1, v2, v3;
        if (j <= OUT_SZ - 4) {           // common: all 4 elems in one row
            const float* prow = tmp + rr * TSTRIDE;
            {   float scf = fminf(fmaxf(((float)(j+0) + 0.5f) * wscale - 0.5f, 0.0f), wmax);
                float cf = floorf(scf); int cc = (int)cf; float wl = scf - cf;
                const float* p = prow + cc; v0 = p[0] + wl * (p[1] - p[0]); }
            {   float scf = fminf(fmaxf(((float)(j+1) + 0.5f) * wscale - 0.5f, 0.0f), wmax);
                float cf = floorf(scf); int cc = (int)cf; float wl = scf - cf;
                const float* p = prow + cc; v1 = p[0] + wl * (p[1] - p[0]); }
            {   float scf = fminf(fmaxf(((float)(j+2) + 0.5f) * wscale - 0.5f, 0.0f), wmax);
                float cf = floorf(scf); int cc = (int)cf; float wl = scf - cf;
                const float* p = prow + cc; v2 = p[0] + wl * (p[1] - p[0]); }
            {   float scf = fminf(fmaxf(((float)(j+3) + 0.5f) * wscale - 0.5f, 0.0f), wmax);
                float cf = floorf(scf); int cc = (int)cf; float wl = scf - cf;
                const float* p = prow + cc; v3 = p[0] + wl * (p[1] - p[0]); }
        } else {                          // seam quad (~1.3% of quads)
            v0 = pix(w); v1 = pix(w + 1); v2 = pix(w + 2); v3 = pix(w + 3);
        }
        *reinterpret_cast<float4*>(ospan + w) = make_float4(v0, v1, v2, v3);
    }
}

extern "C" void kernel_launch(void* const* d_in, const int* in_sizes, int n_in,
                              void* d_out, int out_size, void* d_ws, size_t ws_size,
                              hipStream_t stream) {
    const float* x   = (const float*)d_in[0];  // (32,3,299,299) fp32
    const int*   f   = (const int*)  d_in[1];  // (32,16,4) int32
    float*       out = (float*)d_out;          // (32,16,3,299,299) fp32

    const int nblocks = NXCD * 4 * BLK_PER_IMG;   // 35328 = 23*3*512
    crop_resize_kernel<<<nblocks, NTHR, 0, stream>>>(x, f, out);
}

// Round 17
// 121.181 us; speedup vs baseline: 1.4201x; 1.3701x over previous
//
#include <hip/hip_runtime.h>

#define OUT_SZ 299
#define PLANE (OUT_SZ * OUT_SZ)   // 89401
#define RPB 13                    // output rows per block: 13 * 23 = 299
#define CHUNKS 23
#define TSTRIDE 201               // tmp row stride in dwords (odd; >= wcI+1, wcI<=199)
#define BLK_PER_IMG (16 * 3 * CHUNKS)   // 1104 blocks per image
#define NXCD 8
#define NTHR 320
#define QPR 75                    // column-quads per row (75*4 >= 299)

typedef float f4a4 __attribute__((ext_vector_type(4), aligned(4)));

__global__ __launch_bounds__(NTHR) void crop_resize_kernel(
    const float* __restrict__ x,   // (32, 3, 299, 299)
    const int*   __restrict__ f,   // (32, 16, 4) = tlx, tly, brx, bry
    float*       __restrict__ out) // (32, 16, 3, 299, 299)
{
    __shared__ float tmp[RPB * TSTRIDE];   // 10452 B: row-interped crop rows

    // --- XCD-aware swizzle: all 1104 blocks of an image land on one XCD ---
    const int L       = blockIdx.x;          // 0..35327
    const int xcd     = L & (NXCD - 1);
    const int W       = L >> 3;              // 0..4415
    const int img_grp = W / BLK_PER_IMG;     // 0..3
    const int within  = W - img_grp * BLK_PER_IMG;   // 0..1103
    const int s       = xcd + (img_grp << 3);        // image 0..31
    const int sgl     = within / (3 * CHUNKS);       // crop 0..15
    const int rem     = within - sgl * (3 * CHUNKS);
    const int c       = rem / CHUNKS;                // channel 0..2
    const int chunk   = rem - c * CHUNKS;            // 0..22
    const int sg      = (s << 4) + sgl;

    const int t = threadIdx.x;

    // Box is block-uniform -> scalar loads.
    const int4 box = *reinterpret_cast<const int4*>(f + (size_t)sg * 4);
    const int tlx = box.x, tly = box.y, brx = box.z, bry = box.w;
    const int hcI = brx - tlx, wcI = bry - tly;
    const float hc = (float)hcI, wc = (float)wcI;

    const int i0 = chunk * RPB;

    // Lane table: lanes 0..12 of EVERY wave hold row info for output row i0+rr.
    const int lane = t & 63;
    int v_r0e, v_r1e;
    float v_wr;
    {
        float sr  = fminf(fmaxf(((float)(i0 + lane) + 0.5f) * hc / (float)OUT_SZ
                                - 0.5f, 0.0f), hc - 1.0f);
        float r0f = floorf(sr);
        v_wr = sr - r0f;
        int r0l = (int)r0f;
        int r1l = min(r0l + 1, hcI - 1);
        v_r0e = (r0l + tlx) * OUT_SZ + tly;
        v_r1e = (r1l + tlx) * OUT_SZ + tly;
    }

    // Hoist ALL readlanes into uniform control flow (convergent-op safety).
    int   sr0e[RPB], sr1e[RPB];
    float srw[RPB];
    #pragma unroll
    for (int rr = 0; rr < RPB; ++rr) {
        sr0e[rr] = __builtin_amdgcn_readlane(v_r0e, rr);
        sr1e[rr] = __builtin_amdgcn_readlane(v_r1e, rr);
        srw[rr]  = __int_as_float(
                       __builtin_amdgcn_readlane(__float_as_int(v_wr), rr));
    }

    const float* __restrict__ img = x + ((size_t)s * 3 + (size_t)c) * PLANE;
    const int jl = min(t, wcI - 1);      // phase-1 load col (t==wcI -> pad dup)

    // Phase 1: vertical (row) interp over crop columns — COALESCED loads.
    if (t <= wcI) {
        #pragma unroll
        for (int rr = 0; rr < RPB; ++rr) {
            float a = img[sr0e[rr] + jl];
            float b = img[sr1e[rr] + jl];
            tmp[rr * TSTRIDE + t] = a + srw[rr] * (b - a);
        }
    }
    __syncthreads();
    if (t >= QPR * 4) return;            // 300 threads carry phase 2

    // Phase 2 (transposed): thread owns 4 consecutive output cols, reuses
    // their weights across its rows; writes one dwordx4 per row.
    const int g  = t / QPR;              // row-group 0..3 -> rows g, g+4, g+8, g+12
    const int q  = t - g * QPR;          // column-quad 0..74
    const int c4 = min(4 * q, OUT_SZ - 4);   // quad 74 overlaps 73 at col 295 (benign)

    const float wscale = wc / (float)OUT_SZ;
    const float wmax   = wc - 1.0f;

    int cc0, cc1, cc2, cc3;
    float wl0, wl1, wl2, wl3;
    {   float scf = fminf(fmaxf(((float)(c4+0) + 0.5f) * wscale - 0.5f, 0.0f), wmax);
        float cf = floorf(scf); cc0 = (int)cf; wl0 = scf - cf; }
    {   float scf = fminf(fmaxf(((float)(c4+1) + 0.5f) * wscale - 0.5f, 0.0f), wmax);
        float cf = floorf(scf); cc1 = (int)cf; wl1 = scf - cf; }
    {   float scf = fminf(fmaxf(((float)(c4+2) + 0.5f) * wscale - 0.5f, 0.0f), wmax);
        float cf = floorf(scf); cc2 = (int)cf; wl2 = scf - cf; }
    {   float scf = fminf(fmaxf(((float)(c4+3) + 0.5f) * wscale - 0.5f, 0.0f), wmax);
        float cf = floorf(scf); cc3 = (int)cf; wl3 = scf - cf; }

    float* __restrict__ obase = out + ((size_t)sg * 3 + (size_t)c) * PLANE
                              + (size_t)i0 * OUT_SZ + c4;

    #pragma unroll 4
    for (int rr = g; rr < RPB; rr += 4) {
        const float* __restrict__ prow = tmp + rr * TSTRIDE;
        float a0 = prow[cc0], b0 = prow[cc0 + 1];
        float a1 = prow[cc1], b1 = prow[cc1 + 1];
        float a2 = prow[cc2], b2 = prow[cc2 + 1];
        float a3 = prow[cc3], b3 = prow[cc3 + 1];
        f4a4 v;
        v.x = a0 + wl0 * (b0 - a0);
        v.y = a1 + wl1 * (b1 - a1);
        v.z = a2 + wl2 * (b2 - a2);
        v.w = a3 + wl3 * (b3 - a3);
        *reinterpret_cast<f4a4*>(obase + (size_t)rr * OUT_SZ) = v;
    }
}

extern "C" void kernel_launch(void* const* d_in, const int* in_sizes, int n_in,
                              void* d_out, int out_size, void* d_ws, size_t ws_size,
                              hipStream_t stream) {
    const float* x   = (const float*)d_in[0];  // (32,3,299,299) fp32
    const int*   f   = (const int*)  d_in[1];  // (32,16,4) int32
    float*       out = (float*)d_out;          // (32,16,3,299,299) fp32

    const int nblocks = NXCD * 4 * BLK_PER_IMG;   // 35328 = 23*3*512
    crop_resize_kernel<<<nblocks, NTHR, 0, stream>>>(x, f, out);
}